// Round 1
// baseline (433.436 us; speedup 1.0000x reference)
//
#include <hip/hip_runtime.h>
#include <math.h>

// Problem constants
#define B_   4
#define C_   256
#define H_   200
#define W_   320
#define HW   (H_ * W_)        // 64000
#define BHW  (B_ * HW)        // 256000

// Tiling
#define TH   50               // output tile rows   (200 = 4*50)
#define TW   64               // output tile cols   (320 = 5*64)
#define PR   58               // patch rows  = TH + 8
#define PCW  72               // patch cols  = TW + 8
#define PSTRIDE 76            // padded LDS stride for patch (bank spread, 16B-aligned rows)
#define HSTRIDE 68            // padded LDS stride for hmax
#define CS   16               // channel groups
#define CPG  (C_ / CS)        // 16 channels per group

static_assert(TH * 4 == H_, "H tiling");
static_assert(TW * 5 == W_, "W tiling");

// window-9 max over v[i..i+8] for i=0..7, log-step cascade (5.6 max/output)
__device__ __forceinline__ void win9(const float v[16], float w[8]) {
  float m1[15];
#pragma unroll
  for (int i = 0; i < 15; ++i) m1[i] = fmaxf(v[i], v[i + 1]);   // window 2
  float m2[13];
#pragma unroll
  for (int i = 0; i < 13; ++i) m2[i] = fmaxf(m1[i], m1[i + 2]); // window 4
  float m4[9];
#pragma unroll
  for (int i = 0; i < 9; ++i)  m4[i] = fmaxf(m2[i], m2[i + 4]); // window 8
#pragma unroll
  for (int i = 0; i < 8; ++i)  w[i] = fmaxf(m4[i], v[i + 8]);   // window 9
}

__global__ __launch_bounds__(256) void hdm_main(const float* __restrict__ x,
                                                float* __restrict__ wsM,
                                                float* __restrict__ wsP) {
  __shared__ float patch[PR * PSTRIDE];
  __shared__ float hmax[PR * HSTRIDE];

  const int tile = blockIdx.x;          // 0..19
  const int b    = blockIdx.y;          // 0..3
  const int cg   = blockIdx.z;          // 0..CS-1
  const int th   = tile / 5, tw = tile % 5;
  const int h0 = th * TH, w0 = tw * TW;
  const int tid = (int)threadIdx.x;

  // vpass run assignment: run = rseg*64 + cw ; rows r0..r0+7 (last seg only 2 valid)
  const int rvA   = tid;                 // always < 448
  const int rsegA = rvA >> 6, cwA = rvA & 63;
  const int r0A   = rsegA * 8;           // <= 24 -> kv = 8 always
  const int rvB   = tid + 256;
  const bool actB = rvB < 7 * 64;        // 448 runs total
  const int rsegB = rvB >> 6, cwB = rvB & 63;
  const int r0B   = rsegB * 8;           // 32,40,48
  const int kvB   = (rsegB == 6) ? 2 : 8;

  float accM0[8], accP0[8], accM1[8], accP1[8];
#pragma unroll
  for (int i = 0; i < 8; ++i) {
    accM0[i] = -INFINITY; accP0[i] = 0.f;
    accM1[i] = -INFINITY; accP1[i] = 0.f;
  }

  for (int cc = 0; cc < CPG; ++cc) {
    const int c = cg * CPG + cc;
    const float* xp = x + (size_t)(b * C_ + c) * HW;

    // ---- stage patch (rows [h0-4, h0+53], cols [w0-4, w0+67]), -inf outside
    for (int q = tid; q < PR * 18; q += 256) {   // 18 float4-chunks per row
      const int pr = q / 18, c4 = q % 18;
      const int pc = c4 * 4;
      const int gh = h0 - 4 + pr;
      const int gw = w0 - 4 + pc;
      float4 v;
      if (gh < 0 || gh >= H_) {
        v.x = v.y = v.z = v.w = -INFINITY;
      } else if (gw >= 0 && gw + 3 < W_) {
        v = *reinterpret_cast<const float4*>(xp + (size_t)gh * W_ + gw);
      } else {
        const float* row = xp + (size_t)gh * W_;
        v.x = (gw + 0 >= 0 && gw + 0 < W_) ? row[gw + 0] : -INFINITY;
        v.y = (gw + 1 >= 0 && gw + 1 < W_) ? row[gw + 1] : -INFINITY;
        v.z = (gw + 2 >= 0 && gw + 2 < W_) ? row[gw + 2] : -INFINITY;
        v.w = (gw + 3 >= 0 && gw + 3 < W_) ? row[gw + 3] : -INFINITY;
      }
      *reinterpret_cast<float4*>(&patch[pr * PSTRIDE + pc]) = v;
    }
    __syncthreads();

    // ---- horizontal pass: hmax[r][cw] = max(patch[r][cw..cw+8]), 58x64 outputs
    for (int rr = tid; rr < PR * 8; rr += 256) {
      const int r = rr >> 3, seg = rr & 7;
      const float* prow = &patch[r * PSTRIDE + seg * 8];
      const float4 a0 = *reinterpret_cast<const float4*>(prow + 0);
      const float4 a1 = *reinterpret_cast<const float4*>(prow + 4);
      const float4 a2 = *reinterpret_cast<const float4*>(prow + 8);
      const float4 a3 = *reinterpret_cast<const float4*>(prow + 12);
      const float v[16] = {a0.x, a0.y, a0.z, a0.w, a1.x, a1.y, a1.z, a1.w,
                           a2.x, a2.y, a2.z, a2.w, a3.x, a3.y, a3.z, a3.w};
      float w[8];
      win9(v, w);
      float* hrow = &hmax[r * HSTRIDE + seg * 8];
      *reinterpret_cast<float4*>(hrow + 0) = make_float4(w[0], w[1], w[2], w[3]);
      *reinterpret_cast<float4*>(hrow + 4) = make_float4(w[4], w[5], w[6], w[7]);
    }
    __syncthreads();

    // ---- vertical pass + streaming depth-max/prob accumulate
    {
      float hv[16];
#pragma unroll
      for (int i = 0; i < 16; ++i) hv[i] = hmax[(r0A + i) * HSTRIDE + cwA];
      float w9v[8];
      win9(hv, w9v);
#pragma unroll
      for (int i = 0; i < 8; ++i) {
        const float xc  = patch[(r0A + 4 + i) * PSTRIDE + (cwA + 4)];
        const float add = (xc == w9v[i]) ? xc : 0.f;
        const bool  gt  = xc > accM0[i];
        const bool  eq  = xc == accM0[i];
        accP0[i] = gt ? add : (accP0[i] + (eq ? add : 0.f));
        accM0[i] = gt ? xc : accM0[i];
      }
    }
    if (actB) {
      float hv[16];
#pragma unroll
      for (int i = 0; i < 16; ++i) {
        int r = r0B + i;
        r = (r < PR) ? r : (PR - 1);          // clamp (only last seg over-reads)
        hv[i] = hmax[r * HSTRIDE + cwB];
      }
      float w9v[8];
      win9(hv, w9v);
#pragma unroll
      for (int i = 0; i < 8; ++i) {
        if (i < kvB) {
          const float xc  = patch[(r0B + 4 + i) * PSTRIDE + (cwB + 4)];
          const float add = (xc == w9v[i]) ? xc : 0.f;
          const bool  gt  = xc > accM1[i];
          const bool  eq  = xc == accM1[i];
          accP1[i] = gt ? add : (accP1[i] + (eq ? add : 0.f));
          accM1[i] = gt ? xc : accM1[i];
        }
      }
    }
    __syncthreads();   // protect patch/hmax before next channel's staging
  }

  // ---- write per-group partials
  const size_t obase = (size_t)cg * BHW + (size_t)b * HW;
#pragma unroll
  for (int i = 0; i < 8; ++i) {
    const int h = h0 + r0A + i, w = w0 + cwA;
    const size_t idx = obase + (size_t)h * W_ + w;
    wsM[idx] = accM0[i];
    wsP[idx] = accP0[i];
  }
  if (actB) {
#pragma unroll
    for (int i = 0; i < 8; ++i) {
      if (i < kvB) {
        const int h = h0 + r0B + i, w = w0 + cwB;
        const size_t idx = obase + (size_t)h * W_ + w;
        wsM[idx] = accM1[i];
        wsP[idx] = accP1[i];
      }
    }
  }
}

// exact tie-safe combine over channel groups
__global__ __launch_bounds__(256) void hdm_combine(const float* __restrict__ wsM,
                                                   const float* __restrict__ wsP,
                                                   float* __restrict__ out) {
  const int px = blockIdx.x * 256 + (int)threadIdx.x;
  if (px >= BHW) return;
  float gm = -INFINITY, p = 0.f;
#pragma unroll
  for (int cs = 0; cs < CS; ++cs) {
    const float m = wsM[(size_t)cs * BHW + px];
    const float q = wsP[(size_t)cs * BHW + px];
    const bool gt = m > gm;
    const bool eq = m == gm;
    p  = gt ? q : (p + (eq ? q : 0.f));
    gm = gt ? m : gm;
  }
  out[px] = p;
}

extern "C" void kernel_launch(void* const* d_in, const int* in_sizes, int n_in,
                              void* d_out, int out_size, void* d_ws, size_t ws_size,
                              hipStream_t stream) {
  const float* x = (const float*)d_in[0];
  float* wsM = (float*)d_ws;                       // CS*BHW floats
  float* wsP = wsM + (size_t)CS * BHW;             // CS*BHW floats (total 32.8 MB)
  float* out = (float*)d_out;

  hipLaunchKernelGGL(hdm_main, dim3(20, B_, CS), dim3(256), 0, stream, x, wsM, wsP);
  hipLaunchKernelGGL(hdm_combine, dim3((BHW + 255) / 256), dim3(256), 0, stream,
                     wsM, wsP, out);
}